// Round 7
// baseline (900.044 us; speedup 1.0000x reference)
//
#include <hip/hip_runtime.h>
#include <hip/hip_bf16.h>

typedef __bf16 bf16;
typedef __bf16 v8bf __attribute__((ext_vector_type(8)));
typedef __bf16 v4bf __attribute__((ext_vector_type(4)));
typedef float  v4f  __attribute__((ext_vector_type(4)));

constexpr int NB   = 16;     // batch
constexpr int CIN  = 256;    // channels
constexpr int NPOS = 2304;   // 48*48 spatial positions
constexpr int CHID = 512;    // hidden
constexpr int BCH  = 8;      // batches per A-chunk stage

// ---- workspace layout (bytes) ----
constexpr size_t OFF_WH   = 0;                               // [1024][256] bf16
constexpr size_t OFF_WQK  = OFF_WH   + 1024ull*256*2;        // [192][256] bf16
constexpr size_t OFF_WOUT = OFF_WQK  + 192ull*256*2;         // [256][512] bf16
constexpr size_t OFF_XT   = OFF_WOUT + 256ull*512*2;         // [B][N][256] bf16
constexpr size_t OFF_ZT   = OFF_XT   + (size_t)NB*NPOS*CIN*2;    // [B][N][192] bf16 (q:0..95, k:96..191)
constexpr size_t OFF_VG   = OFF_ZT   + (size_t)NB*NPOS*192*2;    // [B][1024][N] bf16 (v:0..511, gate:512..1023)
constexpr size_t OFF_VT   = OFF_VG   + (size_t)NB*1024*NPOS*2;   // [B][N][512] bf16
constexpr size_t OFF_A    = OFF_VT   + (size_t)NB*NPOS*CHID*2;   // [BCH][N][N] bf16 (chunk-staged)

// ---------------------------------------------------------------------------
// cast weights f32 -> bf16
__global__ void cast_weights(const float* __restrict__ wh, const float* __restrict__ wqk,
                             const float* __restrict__ wo,
                             bf16* __restrict__ whb, bf16* __restrict__ wqkb, bf16* __restrict__ wob) {
    int i = blockIdx.x * 256 + threadIdx.x;
    if (i < 1024*256) whb[i]  = (bf16)wh[i];
    if (i < 192*256)  wqkb[i] = (bf16)wqk[i];
    if (i < 256*512)  wob[i]  = (bf16)wo[i];
}

// ---------------------------------------------------------------------------
// x [B][256][N] f32  ->  xT [B][N][256] bf16
__global__ void transpose_cast_x(const float* __restrict__ x, bf16* __restrict__ xT) {
    __shared__ float tile[32][33];
    const int b = blockIdx.z, c0 = blockIdx.y * 32, n0 = blockIdx.x * 32;
    const int tx = threadIdx.x, ty = threadIdx.y;
    const float* xb = x + (size_t)b * CIN * NPOS;
    bf16* xTb = xT + (size_t)b * NPOS * CIN;
    #pragma unroll
    for (int r = ty; r < 32; r += 8) tile[r][tx] = xb[(size_t)(c0 + r) * NPOS + n0 + tx];
    __syncthreads();
    #pragma unroll
    for (int r = ty; r < 32; r += 8) xTb[(size_t)(n0 + r) * CIN + c0 + tx] = (bf16)tile[tx][r];
}

// ---------------------------------------------------------------------------
// Generic bf16 GEMM: D[m][n] = sum_k A[m][k] * Bt[n][k]   (both operands k-contig)
// MODE 0: silu(D+bias) -> out bf16 [NB][1024][NPOS]      (vg)
// MODE 1: silu(D+bias) -> out bf16 [NB][NPOS][192] (T)   (zT)
// MODE 2: D+bias+resid -> out f32  [NB][256][NPOS]       (final)
template<int MODE>
__global__ __launch_bounds__(256) void gemm_bt(
    const bf16* __restrict__ A, const bf16* __restrict__ Bt,
    const float* __restrict__ bias, void* __restrict__ outp,
    const float* __restrict__ resid, int M, int K)
{
    __shared__ bf16 sA[128][40];   // +8 pad: proven zero-conflict on b128 reads
    __shared__ bf16 sB[128][40];
    const int b = blockIdx.z, mt = blockIdx.x, nt = blockIdx.y;
    const int tid = threadIdx.x;
    const int wave = tid >> 6, lane = tid & 63, lo = lane & 15, hi = lane >> 4;
    const int wr = wave >> 1, wc = wave & 1;

    const bf16* Ab = A  + (size_t)mt * 128 * K;
    const bf16* Bb = Bt + ((size_t)b * NPOS + (size_t)nt * 128) * K;

    const int r0 = tid >> 2, koff = (tid & 3) * 8;
    const int r1 = r0 + 64;
    const int nk = K >> 5;
    const bool a0ok = (mt * 128 + r0) < M;
    const bool a1ok = (mt * 128 + r1) < M;

    v4f acc[4][4];
    #pragma unroll
    for (int i = 0; i < 4; ++i)
        #pragma unroll
        for (int j = 0; j < 4; ++j) acc[i][j] = (v4f){0.f, 0.f, 0.f, 0.f};

    uint4 ra0 = {0,0,0,0}, ra1 = {0,0,0,0}, rb0, rb1;
    if (a0ok) ra0 = *(const uint4*)(Ab + (size_t)r0 * K + koff);
    if (a1ok) ra1 = *(const uint4*)(Ab + (size_t)r1 * K + koff);
    rb0 = *(const uint4*)(Bb + (size_t)r0 * K + koff);
    rb1 = *(const uint4*)(Bb + (size_t)r1 * K + koff);

    for (int kt = 0; kt < nk; ++kt) {
        __syncthreads();
        *(uint4*)&sA[r0][koff] = ra0;
        *(uint4*)&sA[r1][koff] = ra1;
        *(uint4*)&sB[r0][koff] = rb0;
        *(uint4*)&sB[r1][koff] = rb1;
        __syncthreads();
        if (kt + 1 < nk) {
            const int kb = (kt + 1) * 32 + koff;
            if (a0ok) ra0 = *(const uint4*)(Ab + (size_t)r0 * K + kb);
            if (a1ok) ra1 = *(const uint4*)(Ab + (size_t)r1 * K + kb);
            rb0 = *(const uint4*)(Bb + (size_t)r0 * K + kb);
            rb1 = *(const uint4*)(Bb + (size_t)r1 * K + kb);
        }
        v8bf af[4], bfr[4];
        #pragma unroll
        for (int i = 0; i < 4; ++i) af[i]  = *(const v8bf*)&sA[wr * 64 + i * 16 + lo][hi * 8];
        #pragma unroll
        for (int j = 0; j < 4; ++j) bfr[j] = *(const v8bf*)&sB[wc * 64 + j * 16 + lo][hi * 8];
        #pragma unroll
        for (int i = 0; i < 4; ++i)
            #pragma unroll
            for (int j = 0; j < 4; ++j)
                acc[i][j] = __builtin_amdgcn_mfma_f32_16x16x32_bf16(af[i], bfr[j], acc[i][j], 0, 0, 0);
    }

    // epilogue: D row = (lane>>4)*4 + r, col = lane&15  (verified gfx950 mapping)
    #pragma unroll
    for (int i = 0; i < 4; ++i) {
        const int mg0 = mt * 128 + wr * 64 + i * 16 + hi * 4;
        #pragma unroll
        for (int j = 0; j < 4; ++j) {
            const int ng = nt * 128 + wc * 64 + j * 16 + lo;
            #pragma unroll
            for (int r = 0; r < 4; ++r) {
                const int mg = mg0 + r;
                if (mg >= M) continue;
                float v = acc[i][j][r] + bias[mg];
                if (MODE == 0) {
                    v = v / (1.f + __expf(-v));
                    ((bf16*)outp)[((size_t)b * 1024 + mg) * NPOS + ng] = (bf16)v;
                } else if (MODE == 1) {
                    v = v / (1.f + __expf(-v));
                    ((bf16*)outp)[((size_t)b * NPOS + ng) * 192 + mg] = (bf16)v;
                } else {
                    const size_t idx = ((size_t)b * CIN + mg) * NPOS + ng;
                    ((float*)outp)[idx] = v + resid[idx];
                }
            }
        }
    }
}

// ---------------------------------------------------------------------------
// sim_kernel: A[bb][n][m] = relu^2( sum_c q[b][n][c] * k[b][m][c] ), one 8-batch chunk.
// K=96 -> register-direct fragments, no LDS, no barriers. 48 MFMA per block.
__global__ __launch_bounds__(256) void sim_kernel(
    const bf16* __restrict__ zT,    // [NB][NPOS][192] (q:0..95, k:96..191)
    bf16* __restrict__ Abuf,        // [BCH][NPOS][NPOS]
    int b0)
{
    const int bb = blockIdx.z;
    const int ntile = blockIdx.x, mtile = blockIdx.y;
    const int tid = threadIdx.x;
    const int wave = tid >> 6, lane = tid & 63, lo = lane & 15, hi = lane >> 4;
    const int wr = wave >> 1, wc = wave & 1;
    const bf16* zTb = zT + (size_t)(b0 + bb) * NPOS * 192;

    v8bf af[4][3], bfr[4][3];
    #pragma unroll
    for (int i = 0; i < 4; ++i) {
        const bf16* qp = zTb + (size_t)(ntile * 128 + wr * 64 + i * 16 + lo) * 192 + hi * 8;
        #pragma unroll
        for (int c = 0; c < 3; ++c) af[i][c] = *(const v8bf*)(qp + c * 32);
    }
    #pragma unroll
    for (int j = 0; j < 4; ++j) {
        const bf16* kp = zTb + (size_t)(mtile * 128 + wc * 64 + j * 16 + lo) * 192 + 96 + hi * 8;
        #pragma unroll
        for (int c = 0; c < 3; ++c) bfr[j][c] = *(const v8bf*)(kp + c * 32);
    }

    v4f acc[4][4];
    #pragma unroll
    for (int i = 0; i < 4; ++i)
        #pragma unroll
        for (int j = 0; j < 4; ++j) acc[i][j] = (v4f){0.f, 0.f, 0.f, 0.f};
    #pragma unroll
    for (int c = 0; c < 3; ++c)
        #pragma unroll
        for (int i = 0; i < 4; ++i)
            #pragma unroll
            for (int j = 0; j < 4; ++j)
                acc[i][j] = __builtin_amdgcn_mfma_f32_16x16x32_bf16(af[i][c], bfr[j][c], acc[i][j], 0, 0, 0);

    bf16* Ab = Abuf + (size_t)bb * NPOS * NPOS;
    #pragma unroll
    for (int i = 0; i < 4; ++i) {
        const int n0 = ntile * 128 + wr * 64 + i * 16 + hi * 4;
        #pragma unroll
        for (int r = 0; r < 4; ++r) {
            bf16* row = Ab + (size_t)(n0 + r) * NPOS + mtile * 128 + wc * 64 + lo;
            #pragma unroll
            for (int j = 0; j < 4; ++j) {
                float t = acc[i][j][r];
                t = t > 0.f ? t * t : 0.f;     // relu^2
                row[j * 16] = (bf16)t;
            }
        }
    }
}

// ---------------------------------------------------------------------------
// gemm_pv: Vf[h][n] = sum_m v[h][m] * A[n][m]; fused gate; store VT[b][n][h].
// M=512 (h-tiles of 128, mt=0..3), N=2304 (nt=0..17), K=2304, BK=64.
__global__ __launch_bounds__(256) void gemm_pv(
    const bf16* __restrict__ vg,    // [NB][1024][NPOS] (v:0..511, gate:512..1023)
    const bf16* __restrict__ Abuf,  // [BCH][NPOS][NPOS]
    bf16* __restrict__ VT,          // [NB][NPOS][512]
    int b0)
{
    __shared__ bf16 sA[128][76];   // 152B rows: stride-38 banks, all 16 lo-lanes distinct
    __shared__ bf16 sB[128][76];
    const int bb = blockIdx.z, b = b0 + bb;
    const int mt = blockIdx.x, nt = blockIdx.y;
    const int tid = threadIdx.x;
    const int wave = tid >> 6, lane = tid & 63, lo = lane & 15, hi = lane >> 4;
    const int wr = wave >> 1, wc = wave & 1;

    const bf16* vb = vg + (size_t)b * 1024 * NPOS;
    const bf16* Ab = vb + (size_t)mt * 128 * NPOS;                        // v rows (h)
    const bf16* Bb = Abuf + ((size_t)bb * NPOS + (size_t)nt * 128) * NPOS; // A rows (n)

    const int r0 = tid >> 3;             // 0..31: rows r0, r0+32, r0+64, r0+96
    const int koff = (tid & 7) * 8;      // bf16 elems within 64-wide k-tile

    v4f acc[4][4];
    #pragma unroll
    for (int i = 0; i < 4; ++i)
        #pragma unroll
        for (int j = 0; j < 4; ++j) acc[i][j] = (v4f){0.f, 0.f, 0.f, 0.f};

    uint4 ra[4], rb[4];
    #pragma unroll
    for (int q = 0; q < 4; ++q) {
        ra[q] = *(const uint4*)(Ab + (size_t)(r0 + q * 32) * NPOS + koff);
        rb[q] = *(const uint4*)(Bb + (size_t)(r0 + q * 32) * NPOS + koff);
    }

    for (int kt = 0; kt < NPOS / 64; ++kt) {
        __syncthreads();
        #pragma unroll
        for (int q = 0; q < 4; ++q) {
            *(uint4*)&sA[r0 + q * 32][koff] = ra[q];
            *(uint4*)&sB[r0 + q * 32][koff] = rb[q];
        }
        __syncthreads();
        if (kt + 1 < NPOS / 64) {
            const int kb = (kt + 1) * 64 + koff;
            #pragma unroll
            for (int q = 0; q < 4; ++q) {
                ra[q] = *(const uint4*)(Ab + (size_t)(r0 + q * 32) * NPOS + kb);
                rb[q] = *(const uint4*)(Bb + (size_t)(r0 + q * 32) * NPOS + kb);
            }
        }
        #pragma unroll
        for (int kk = 0; kk < 2; ++kk) {
            v8bf af[4], bfr[4];
            #pragma unroll
            for (int i = 0; i < 4; ++i) af[i]  = *(const v8bf*)&sA[wr * 64 + i * 16 + lo][kk * 32 + hi * 8];
            #pragma unroll
            for (int j = 0; j < 4; ++j) bfr[j] = *(const v8bf*)&sB[wc * 64 + j * 16 + lo][kk * 32 + hi * 8];
            #pragma unroll
            for (int i = 0; i < 4; ++i)
                #pragma unroll
                for (int j = 0; j < 4; ++j)
                    acc[i][j] = __builtin_amdgcn_mfma_f32_16x16x32_bf16(af[i], bfr[j], acc[i][j], 0, 0, 0);
        }
    }

    // epilogue: h = mt*128 + wr*64 + i*16 + hi*4 + r;  n = nt*128 + wc*64 + j*16 + lo
    // V = acc * gate; store 4 consecutive h per lane (8B)
    #pragma unroll
    for (int i = 0; i < 4; ++i) {
        const int hb = mt * 128 + wr * 64 + i * 16 + hi * 4;
        #pragma unroll
        for (int j = 0; j < 4; ++j) {
            const int n = nt * 128 + wc * 64 + j * 16 + lo;
            v4bf outv;
            #pragma unroll
            for (int r = 0; r < 4; ++r) {
                const float g = (float)vb[(size_t)(512 + hb + r) * NPOS + n];
                outv[r] = (bf16)(acc[i][j][r] * g);
            }
            *(v4bf*)&VT[((size_t)b * NPOS + n) * CHID + hb] = outv;
        }
    }
}

// ---------------------------------------------------------------------------
extern "C" void kernel_launch(void* const* d_in, const int* in_sizes, int n_in,
                              void* d_out, int out_size, void* d_ws, size_t ws_size,
                              hipStream_t stream) {
    const float* x   = (const float*)d_in[0];
    const float* wh  = (const float*)d_in[1];
    const float* bh  = (const float*)d_in[2];
    const float* wqk = (const float*)d_in[3];
    const float* bqk = (const float*)d_in[4];
    const float* wo  = (const float*)d_in[5];
    const float* bo  = (const float*)d_in[6];

    char* ws = (char*)d_ws;
    bf16* whb  = (bf16*)(ws + OFF_WH);
    bf16* wqkb = (bf16*)(ws + OFF_WQK);
    bf16* wob  = (bf16*)(ws + OFF_WOUT);
    bf16* xT   = (bf16*)(ws + OFF_XT);
    bf16* zT   = (bf16*)(ws + OFF_ZT);
    bf16* vg   = (bf16*)(ws + OFF_VG);
    bf16* VT   = (bf16*)(ws + OFF_VT);
    bf16* Abuf = (bf16*)(ws + OFF_A);

    cast_weights<<<1024, 256, 0, stream>>>(wh, wqk, wo, whb, wqkb, wob);
    transpose_cast_x<<<dim3(72, 8, 16), dim3(32, 8), 0, stream>>>(x, xT);
    // hid = silu(Wh x + bh): v rows 0..511, gate rows 512..1023
    gemm_bt<0><<<dim3(8, 18, 16), 256, 0, stream>>>(whb, xT, bh, vg, nullptr, 1024, 256);
    // z = silu(Wqk x + bqk), stored transposed: q cols 0..95, k cols 96..191
    gemm_bt<1><<<dim3(2, 18, 16), 256, 0, stream>>>(wqkb, xT, bqk, zT, nullptr, 192, 256);
    // attention in two 8-batch chunks: A = relu^2(q k^T) materialized, then PV GEMM + gate
    for (int c = 0; c < NB / BCH; ++c) {
        const int b0 = c * BCH;
        sim_kernel<<<dim3(18, 18, BCH), 256, 0, stream>>>(zT, Abuf, b0);
        gemm_pv<<<dim3(4, 18, BCH), 256, 0, stream>>>(vg, Abuf, VT, b0);
    }
    // out = Wout V + bo + x
    gemm_bt<2><<<dim3(2, 18, 16), 256, 0, stream>>>(wob, VT, bo, d_out, x, 256, 512);
}

// Round 10
// 485.782 us; speedup vs baseline: 1.8528x; 1.8528x over previous
//
#include <hip/hip_runtime.h>
#include <hip/hip_bf16.h>

typedef __bf16 bf16;
typedef __bf16 v8bf __attribute__((ext_vector_type(8)));
typedef __bf16 v4bf __attribute__((ext_vector_type(4)));
typedef float  v4f  __attribute__((ext_vector_type(4)));

constexpr int NB   = 16;     // batch
constexpr int CIN  = 256;    // channels
constexpr int NPOS = 2304;   // 48*48 spatial positions
constexpr int CHID = 512;    // hidden
constexpr int BCH  = 8;      // batches per A-chunk stage

// ---- workspace layout (bytes) ----
constexpr size_t OFF_WH   = 0;                               // [1024][256] bf16
constexpr size_t OFF_WQK  = OFF_WH   + 1024ull*256*2;        // [192][256] bf16
constexpr size_t OFF_WOUT = OFF_WQK  + 192ull*256*2;         // [256][512] bf16
constexpr size_t OFF_XT   = OFF_WOUT + 256ull*512*2;         // [B][N][256] bf16
constexpr size_t OFF_ZT   = OFF_XT   + (size_t)NB*NPOS*CIN*2;    // [B][N][192] bf16 (q:0..95, k:96..191)
constexpr size_t OFF_VG   = OFF_ZT   + (size_t)NB*NPOS*192*2;    // [B][1024][N] bf16 (v:0..511, gate:512..1023)
constexpr size_t OFF_VT   = OFF_VG   + (size_t)NB*1024*NPOS*2;   // [B][N][512] bf16
constexpr size_t OFF_A    = OFF_VT   + (size_t)NB*NPOS*CHID*2;   // [BCH][N][N] bf16 (chunk-staged)

// ---------------------------------------------------------------------------
// cast weights f32 -> bf16
__global__ void cast_weights(const float* __restrict__ wh, const float* __restrict__ wqk,
                             const float* __restrict__ wo,
                             bf16* __restrict__ whb, bf16* __restrict__ wqkb, bf16* __restrict__ wob) {
    int i = blockIdx.x * 256 + threadIdx.x;
    if (i < 1024*256) whb[i]  = (bf16)wh[i];
    if (i < 192*256)  wqkb[i] = (bf16)wqk[i];
    if (i < 256*512)  wob[i]  = (bf16)wo[i];
}

// ---------------------------------------------------------------------------
// x [B][256][N] f32  ->  xT [B][N][256] bf16
__global__ void transpose_cast_x(const float* __restrict__ x, bf16* __restrict__ xT) {
    __shared__ float tile[32][33];
    const int b = blockIdx.z, c0 = blockIdx.y * 32, n0 = blockIdx.x * 32;
    const int tx = threadIdx.x, ty = threadIdx.y;
    const float* xb = x + (size_t)b * CIN * NPOS;
    bf16* xTb = xT + (size_t)b * NPOS * CIN;
    #pragma unroll
    for (int r = ty; r < 32; r += 8) tile[r][tx] = xb[(size_t)(c0 + r) * NPOS + n0 + tx];
    __syncthreads();
    #pragma unroll
    for (int r = ty; r < 32; r += 8) xTb[(size_t)(n0 + r) * CIN + c0 + tx] = (bf16)tile[tx][r];
}

// ---------------------------------------------------------------------------
// Generic bf16 GEMM: D[m][n] = sum_k A[m][k] * Bt[n][k]   (both operands k-contig)
// MODE 0: silu(D+bias) -> out bf16 [NB][1024][NPOS]      (vg)
// MODE 1: silu(D+bias) -> out bf16 [NB][NPOS][192] (T)   (zT)
// MODE 2: D+bias+resid -> out f32  [NB][256][NPOS]       (final)
template<int MODE>
__global__ __launch_bounds__(256) void gemm_bt(
    const bf16* __restrict__ A, const bf16* __restrict__ Bt,
    const float* __restrict__ bias, void* __restrict__ outp,
    const float* __restrict__ resid, int M, int K)
{
    __shared__ bf16 sA[128][40];   // +8 pad: proven zero-conflict on b128 reads
    __shared__ bf16 sB[128][40];
    const int b = blockIdx.z, mt = blockIdx.x, nt = blockIdx.y;
    const int tid = threadIdx.x;
    const int wave = tid >> 6, lane = tid & 63, lo = lane & 15, hi = lane >> 4;
    const int wr = wave >> 1, wc = wave & 1;

    const bf16* Ab = A  + (size_t)mt * 128 * K;
    const bf16* Bb = Bt + ((size_t)b * NPOS + (size_t)nt * 128) * K;

    const int r0 = tid >> 2, koff = (tid & 3) * 8;
    const int r1 = r0 + 64;
    const int nk = K >> 5;
    const bool a0ok = (mt * 128 + r0) < M;
    const bool a1ok = (mt * 128 + r1) < M;

    v4f acc[4][4];
    #pragma unroll
    for (int i = 0; i < 4; ++i)
        #pragma unroll
        for (int j = 0; j < 4; ++j) acc[i][j] = (v4f){0.f, 0.f, 0.f, 0.f};

    uint4 ra0 = {0,0,0,0}, ra1 = {0,0,0,0}, rb0, rb1;
    if (a0ok) ra0 = *(const uint4*)(Ab + (size_t)r0 * K + koff);
    if (a1ok) ra1 = *(const uint4*)(Ab + (size_t)r1 * K + koff);
    rb0 = *(const uint4*)(Bb + (size_t)r0 * K + koff);
    rb1 = *(const uint4*)(Bb + (size_t)r1 * K + koff);

    for (int kt = 0; kt < nk; ++kt) {
        __syncthreads();
        *(uint4*)&sA[r0][koff] = ra0;
        *(uint4*)&sA[r1][koff] = ra1;
        *(uint4*)&sB[r0][koff] = rb0;
        *(uint4*)&sB[r1][koff] = rb1;
        __syncthreads();
        if (kt + 1 < nk) {
            const int kb = (kt + 1) * 32 + koff;
            if (a0ok) ra0 = *(const uint4*)(Ab + (size_t)r0 * K + kb);
            if (a1ok) ra1 = *(const uint4*)(Ab + (size_t)r1 * K + kb);
            rb0 = *(const uint4*)(Bb + (size_t)r0 * K + kb);
            rb1 = *(const uint4*)(Bb + (size_t)r1 * K + kb);
        }
        v8bf af[4], bfr[4];
        #pragma unroll
        for (int i = 0; i < 4; ++i) af[i]  = *(const v8bf*)&sA[wr * 64 + i * 16 + lo][hi * 8];
        #pragma unroll
        for (int j = 0; j < 4; ++j) bfr[j] = *(const v8bf*)&sB[wc * 64 + j * 16 + lo][hi * 8];
        #pragma unroll
        for (int i = 0; i < 4; ++i)
            #pragma unroll
            for (int j = 0; j < 4; ++j)
                acc[i][j] = __builtin_amdgcn_mfma_f32_16x16x32_bf16(af[i], bfr[j], acc[i][j], 0, 0, 0);
    }

    // epilogue: D row = (lane>>4)*4 + r, col = lane&15  (verified gfx950 mapping)
    #pragma unroll
    for (int i = 0; i < 4; ++i) {
        const int mg0 = mt * 128 + wr * 64 + i * 16 + hi * 4;
        #pragma unroll
        for (int j = 0; j < 4; ++j) {
            const int ng = nt * 128 + wc * 64 + j * 16 + lo;
            #pragma unroll
            for (int r = 0; r < 4; ++r) {
                const int mg = mg0 + r;
                if (mg >= M) continue;
                float v = acc[i][j][r] + bias[mg];
                if (MODE == 0) {
                    v = v / (1.f + __expf(-v));
                    ((bf16*)outp)[((size_t)b * 1024 + mg) * NPOS + ng] = (bf16)v;
                } else if (MODE == 1) {
                    v = v / (1.f + __expf(-v));
                    ((bf16*)outp)[((size_t)b * NPOS + ng) * 192 + mg] = (bf16)v;
                } else {
                    const size_t idx = ((size_t)b * CIN + mg) * NPOS + ng;
                    ((float*)outp)[idx] = v + resid[idx];
                }
            }
        }
    }
}

// ---------------------------------------------------------------------------
// sim_kernel: A[bb][n][m] = relu^2( sum_c q[b][n][c] * k[b][m][c] ), one 8-batch chunk.
// K=96 -> register-direct fragments, no LDS, no barriers. 48 MFMA per block.
__global__ __launch_bounds__(256) void sim_kernel(
    const bf16* __restrict__ zT,    // [NB][NPOS][192] (q:0..95, k:96..191)
    bf16* __restrict__ Abuf,        // [BCH][NPOS][NPOS]
    int b0)
{
    const int bb = blockIdx.z;
    const int ntile = blockIdx.x, mtile = blockIdx.y;
    const int tid = threadIdx.x;
    const int wave = tid >> 6, lane = tid & 63, lo = lane & 15, hi = lane >> 4;
    const int wr = wave >> 1, wc = wave & 1;
    const bf16* zTb = zT + (size_t)(b0 + bb) * NPOS * 192;

    v8bf af[4][3], bfr[4][3];
    #pragma unroll
    for (int i = 0; i < 4; ++i) {
        const bf16* qp = zTb + (size_t)(ntile * 128 + wr * 64 + i * 16 + lo) * 192 + hi * 8;
        #pragma unroll
        for (int c = 0; c < 3; ++c) af[i][c] = *(const v8bf*)(qp + c * 32);
    }
    #pragma unroll
    for (int j = 0; j < 4; ++j) {
        const bf16* kp = zTb + (size_t)(mtile * 128 + wc * 64 + j * 16 + lo) * 192 + 96 + hi * 8;
        #pragma unroll
        for (int c = 0; c < 3; ++c) bfr[j][c] = *(const v8bf*)(kp + c * 32);
    }

    v4f acc[4][4];
    #pragma unroll
    for (int i = 0; i < 4; ++i)
        #pragma unroll
        for (int j = 0; j < 4; ++j) acc[i][j] = (v4f){0.f, 0.f, 0.f, 0.f};
    #pragma unroll
    for (int c = 0; c < 3; ++c)
        #pragma unroll
        for (int i = 0; i < 4; ++i)
            #pragma unroll
            for (int j = 0; j < 4; ++j)
                acc[i][j] = __builtin_amdgcn_mfma_f32_16x16x32_bf16(af[i][c], bfr[j][c], acc[i][j], 0, 0, 0);

    bf16* Ab = Abuf + (size_t)bb * NPOS * NPOS;
    #pragma unroll
    for (int i = 0; i < 4; ++i) {
        const int n0 = ntile * 128 + wr * 64 + i * 16 + hi * 4;
        #pragma unroll
        for (int r = 0; r < 4; ++r) {
            bf16* row = Ab + (size_t)(n0 + r) * NPOS + mtile * 128 + wc * 64 + lo;
            #pragma unroll
            for (int j = 0; j < 4; ++j) {
                float t = acc[i][j][r];
                t = t > 0.f ? t * t : 0.f;     // relu^2
                row[j * 16] = (bf16)t;
            }
        }
    }
}

// ---------------------------------------------------------------------------
// gemm_pv (v2): D[n][h] = sum_m A[n][m] * v[h][m]; fused gate; store VT[b][n][h].
// M-side = n (A rows in sA), N-side = h (v rows in sB). BK=32, [128][40] LDS (20KB).
// 1-D grid 576 with bijective XCD chunking: logical = (phys%8)*72 + phys/8;
// each XCD owns one batch; the 4 nt-blocks sharing an A-panel are adjacent.
// Epilogue: lanes write consecutive h -> coalesced VT lines; gate applied here.
__global__ __launch_bounds__(256, 2) void gemm_pv(
    const bf16* __restrict__ vg,    // [NB][1024][NPOS] (v:0..511, gate:512..1023)
    const bf16* __restrict__ Abuf,  // [BCH][NPOS][NPOS]
    bf16* __restrict__ VT,          // [NB][NPOS][512]
    int b0)
{
    __shared__ bf16 sA[128][40];
    __shared__ bf16 sB[128][40];
    const int phys = blockIdx.x;
    const int L  = (phys & 7) * 72 + (phys >> 3);   // 576 = 8 * 72, bijective
    const int nt = L & 3;            // h-tile 0..3
    const int mt = (L >> 2) % 18;    // n-tile 0..17
    const int bb = L / 72;           // batch-in-chunk 0..7 (one per XCD)
    const int b  = b0 + bb;
    const int tid = threadIdx.x;
    const int wave = tid >> 6, lane = tid & 63, lo = lane & 15, hi = lane >> 4;
    const int wr = wave >> 1, wc = wave & 1;

    const bf16* vb = vg + (size_t)b * 1024 * NPOS;
    const bf16* Ab = Abuf + ((size_t)bb * NPOS + (size_t)mt * 128) * NPOS;  // A[n][m] rows
    const bf16* Vb = vb + (size_t)(nt * 128) * NPOS;                        // v[h][m] rows

    const int r0 = tid >> 2, koff = (tid & 3) * 8;   // [128 rows][32 k]: 4 threads/row
    const int r1 = r0 + 64;

    v4f acc[4][4];
    #pragma unroll
    for (int i = 0; i < 4; ++i)
        #pragma unroll
        for (int j = 0; j < 4; ++j) acc[i][j] = (v4f){0.f, 0.f, 0.f, 0.f};

    uint4 ra0, ra1, rb0, rb1;
    ra0 = *(const uint4*)(Ab + (size_t)r0 * NPOS + koff);
    ra1 = *(const uint4*)(Ab + (size_t)r1 * NPOS + koff);
    rb0 = *(const uint4*)(Vb + (size_t)r0 * NPOS + koff);
    rb1 = *(const uint4*)(Vb + (size_t)r1 * NPOS + koff);

    constexpr int NK = NPOS / 32;   // 72
    for (int kt = 0; kt < NK; ++kt) {
        __syncthreads();
        *(uint4*)&sA[r0][koff] = ra0;
        *(uint4*)&sA[r1][koff] = ra1;
        *(uint4*)&sB[r0][koff] = rb0;
        *(uint4*)&sB[r1][koff] = rb1;
        __syncthreads();
        if (kt + 1 < NK) {
            const int kb = (kt + 1) * 32 + koff;
            ra0 = *(const uint4*)(Ab + (size_t)r0 * NPOS + kb);
            ra1 = *(const uint4*)(Ab + (size_t)r1 * NPOS + kb);
            rb0 = *(const uint4*)(Vb + (size_t)r0 * NPOS + kb);
            rb1 = *(const uint4*)(Vb + (size_t)r1 * NPOS + kb);
        }
        v8bf af[4], bfr[4];
        #pragma unroll
        for (int i = 0; i < 4; ++i) af[i]  = *(const v8bf*)&sA[wr * 64 + i * 16 + lo][hi * 8];
        #pragma unroll
        for (int j = 0; j < 4; ++j) bfr[j] = *(const v8bf*)&sB[wc * 64 + j * 16 + lo][hi * 8];
        #pragma unroll
        for (int i = 0; i < 4; ++i)
            #pragma unroll
            for (int j = 0; j < 4; ++j)
                acc[i][j] = __builtin_amdgcn_mfma_f32_16x16x32_bf16(af[i], bfr[j], acc[i][j], 0, 0, 0);
    }

    // epilogue: n = mt*128 + wr*64 + i*16 + hi*4 + r;  h = nt*128 + wc*64 + j*16 + lo
    // lanes write consecutive h -> coalesced; gate g[h][n] scatter-read once
    #pragma unroll
    for (int i = 0; i < 4; ++i) {
        const int nb_ = mt * 128 + wr * 64 + i * 16 + hi * 4;
        #pragma unroll
        for (int r = 0; r < 4; ++r) {
            const int n = nb_ + r;
            const size_t vtrow = ((size_t)b * NPOS + n) * CHID;
            #pragma unroll
            for (int j = 0; j < 4; ++j) {
                const int h = nt * 128 + wc * 64 + j * 16 + lo;
                const float g = (float)vb[(size_t)(512 + h) * NPOS + n];
                VT[vtrow + h] = (bf16)(acc[i][j][r] * g);
            }
        }
    }
}

// ---------------------------------------------------------------------------
extern "C" void kernel_launch(void* const* d_in, const int* in_sizes, int n_in,
                              void* d_out, int out_size, void* d_ws, size_t ws_size,
                              hipStream_t stream) {
    const float* x   = (const float*)d_in[0];
    const float* wh  = (const float*)d_in[1];
    const float* bh  = (const float*)d_in[2];
    const float* wqk = (const float*)d_in[3];
    const float* bqk = (const float*)d_in[4];
    const float* wo  = (const float*)d_in[5];
    const float* bo  = (const float*)d_in[6];

    char* ws = (char*)d_ws;
    bf16* whb  = (bf16*)(ws + OFF_WH);
    bf16* wqkb = (bf16*)(ws + OFF_WQK);
    bf16* wob  = (bf16*)(ws + OFF_WOUT);
    bf16* xT   = (bf16*)(ws + OFF_XT);
    bf16* zT   = (bf16*)(ws + OFF_ZT);
    bf16* vg   = (bf16*)(ws + OFF_VG);
    bf16* VT   = (bf16*)(ws + OFF_VT);
    bf16* Abuf = (bf16*)(ws + OFF_A);

    cast_weights<<<1024, 256, 0, stream>>>(wh, wqk, wo, whb, wqkb, wob);
    transpose_cast_x<<<dim3(72, 8, 16), dim3(32, 8), 0, stream>>>(x, xT);
    // hid = silu(Wh x + bh): v rows 0..511, gate rows 512..1023
    gemm_bt<0><<<dim3(8, 18, 16), 256, 0, stream>>>(whb, xT, bh, vg, nullptr, 1024, 256);
    // z = silu(Wqk x + bqk), stored transposed: q cols 0..95, k cols 96..191
    gemm_bt<1><<<dim3(2, 18, 16), 256, 0, stream>>>(wqkb, xT, bqk, zT, nullptr, 192, 256);
    // attention in two 8-batch chunks: A = relu^2(q k^T) materialized, then PV GEMM + gate
    for (int c = 0; c < NB / BCH; ++c) {
        const int b0 = c * BCH;
        sim_kernel<<<dim3(18, 18, BCH), 256, 0, stream>>>(zT, Abuf, b0);
        gemm_pv<<<576, 256, 0, stream>>>(vg, Abuf, VT, b0);
    }
    // out = Wout V + bo + x
    gemm_bt<2><<<dim3(2, 18, 16), 256, 0, stream>>>(wob, VT, bo, d_out, x, 256, 512);
}